// Round 7
// baseline (17756.085 us; speedup 1.0000x reference)
//
#include <hip/hip_runtime.h>
#include <math.h>

// LSTM_53171695124900: 2-layer LSTM, H=1024, I=64, O=2, T=4096.
// Persistent kernel, 256 WGs x 512 threads (1 WG/CU, 2 waves/SIMD).
// Round-7 change vs round-6 (17.3ms): the allocator has refused 96
// loop-carried weight floats five times (VGPR 132/140/92/84/88) -> split
// storage to match the ~88-reg budget it insists on:
//   - W_hh1 (32 f/thread) stays in registers (8 float4 SSA + pins)
//   - W_ih2 + W_hh2 (64 f/thread, 128KB/WG) live in LDS f32, staged once,
//     conflict-free [j*512+tid] float4 layout (consecutive lanes -> 16B)
//   - dynamic shared memory 140288B via hipFuncSetAttribute (>64KB default)
// Tagged-pair dataflow sync from r6 kept byte-identical (proven: 1.5x win,
// absmax 6.1e-5): h published as {f32,phase-tag} 8B atomics, consumers poll
// exactly the 16B they need; no grid barrier at all.

#define HID 1024
#define DIN 64
#define TSTEPS 4096
#define NWG 256
#define TPB 512

typedef unsigned long long u64;
typedef unsigned int u32;

// ws layout in u64 (8B tagged pairs):
//   [0, 2048)                 : h1 pairs, 2 slots x 1024
//   [2048, 2048 + 4097*1024)  : h2 pairs; hist mode = row per phase,
//                               fallback mode = rows (phase & 1)
#define H2_OFF 2048
#define WS_NEED_U64 (2048ull + 4097ull * 1024ull)
#define WS_NEED_BYTES (WS_NEED_U64 * 8ull)
#define WS_ZERO_BYTES 32768   // h1 slots (16KB) + h2 rows 0..1 (16KB)

// dynamic LDS: 16*512 float4 weights (128KB) + h1s/h2s staging (9216B)
#define WLDS_F4 (16 * 512)
#define DYN_LDS_BYTES (WLDS_F4 * 16 + 2 * 1152 * 4)

__device__ __forceinline__ float sigmoid_f(float v) {
    return 1.0f / (1.0f + __expf(-v));
}
__device__ __forceinline__ float tanh_f(float v) {
    return 2.0f / (1.0f + __expf(-2.0f * v)) - 1.0f;
}

// relaxed agent-scope 8B atomics: coherent at IC, no cache-maintenance insts
__device__ __forceinline__ void st_pair(u64* p, float h, u32 tag) {
    u64 pk = ((u64)tag << 32) | (u64)__float_as_uint(h);
    __hip_atomic_store(p, pk, __ATOMIC_RELAXED, __HIP_MEMORY_SCOPE_AGENT);
}
__device__ __forceinline__ u64 ld_pair(const u64* p) {
    return __hip_atomic_load(p, __ATOMIC_RELAXED, __HIP_MEMORY_SCOPE_AGENT);
}
#define PTAG(v) ((u32)((v) >> 32))
#define PVAL(v) (__uint_as_float((u32)(v)))

#define PIN4(v) asm volatile("" : "+v"((v).x), "+v"((v).y), "+v"((v).z), "+v"((v).w))
#define PIN_W1() do { \
    PIN4(w1a); PIN4(w1b); PIN4(w1c); PIN4(w1d); \
    PIN4(w1e); PIN4(w1f); PIN4(w1g); PIN4(w1h); \
} while (0)

// one 4-elem k-chunk, step j: W1 from registers, W2/W3 from LDS
#define GSTEP(j, W1) do {                                           \
    float4 hv = *(const float4*)(hb + 4*(j));                       \
    float4 gv = *(const float4*)(gb + 4*(j));                       \
    float4 w2 = wlds[(j)*512 + tid];                                \
    float4 w3 = wlds[(8+(j))*512 + tid];                            \
    a0 = fmaf((W1).x, hv.x, a0); a1 = fmaf((W1).y, hv.y, a1);       \
    a2 = fmaf((W1).z, hv.z, a2); a3 = fmaf((W1).w, hv.w, a3);       \
    e0 = fmaf(w2.x, hv.x, e0); e1 = fmaf(w2.y, hv.y, e1);           \
    e2 = fmaf(w2.z, hv.z, e2); e3 = fmaf(w2.w, hv.w, e3);           \
    e0 = fmaf(w3.x, gv.x, e0); e1 = fmaf(w3.y, gv.y, e1);           \
    e2 = fmaf(w3.z, gv.z, e2); e3 = fmaf(w3.w, gv.w, e3);           \
} while (0)

__global__ void
__attribute__((amdgpu_flat_work_group_size(TPB, TPB), amdgpu_waves_per_eu(2, 2)))
lstm_persistent(
    const float* __restrict__ x,
    const float* __restrict__ Wih1, const float* __restrict__ Whh1,
    const float* __restrict__ bih1, const float* __restrict__ bhh1,
    const float* __restrict__ Wih2, const float* __restrict__ Whh2,
    const float* __restrict__ bih2, const float* __restrict__ bhh2,
    const float* __restrict__ Wout, const float* __restrict__ bout,
    float* __restrict__ out, u64* __restrict__ ws, int use_hist)
{
    const int wg   = blockIdx.x;          // 0..255
    const int tid  = threadIdx.x;         // 0..511
    const int wave = tid >> 6;            // 0..7
    const int lane = tid & 63;
    const int gate = tid >> 7;            // 0..3 (i,f,g,o)
    const int rsub = (tid >> 5) & 3;      // local unit 0..3
    const int c    = tid & 31;            // k-chunk 0..31
    const int row  = gate * HID + (wg << 2) + rsub;   // gate row in [0,4096)
    const int kbase = c << 5;

    u64* h1t = ws;
    u64* h2t = ws + H2_OFF;

    // ---- dynamic LDS carve ----
    extern __shared__ __align__(16) char smem[];
    float4* wlds = (float4*)smem;                         // 128KB weights
    float*  h1s  = (float*)(smem + WLDS_F4 * 16);         // 1152 f32
    float*  h2s  = h1s + 1152;                            // 1152 f32

    // ---- one-time: stage W_ih2/W_hh2 rows into LDS (conflict-free) ----
    {
        const float4* q2 = (const float4*)(Wih2 + (size_t)row * HID + kbase);
        const float4* q3 = (const float4*)(Whh2 + (size_t)row * HID + kbase);
        #pragma unroll
        for (int j = 0; j < 8; ++j) wlds[j * 512 + tid] = q2[j];
        #pragma unroll
        for (int j = 0; j < 8; ++j) wlds[(8 + j) * 512 + tid] = q3[j];
    }

    // ---- W_hh1 row chunk in registers: 8 named float4 SSA values ----
    const float4* p1 = (const float4*)(Whh1 + (size_t)row * HID + kbase);
    float4 w1a = p1[0], w1b = p1[1], w1c = p1[2], w1d = p1[3];
    float4 w1e = p1[4], w1f = p1[5], w1g = p1[6], w1h = p1[7];
    PIN_W1();

    const float2 wx = *(const float2*)(Wih1 + (size_t)row * DIN + (c << 1));
    const float bsum1 = bih1[row] + bhh1[row];
    const float bsum2 = bih2[row] + bhh2[row];

    __shared__ float g1[4][4], g2[4][4];
    __shared__ float c1s[4], c2s[4];
    __shared__ float red0[8], red1[8];
    if (tid < 4) { c1s[tid] = 0.0f; c2s[tid] = 0.0f; }

    // element e=2*tid lands at 36*(e>>5) + (e&31); read base 36*c
    const int sdst = 36 * (tid >> 4) + ((tid << 1) & 31);
    const int sbase = 36 * c;

    __syncthreads();   // wlds staged

    for (int p = 0; p <= TSTEPS; ++p) {
        // ---- tagged poll: h1(p-1) from slot p&1 (tag p);
        //      h2(p-2) from row p-1 (hist) / (p-1)&1 (fallback), tag p (p>=2)
        const u64* h1p = h1t + (size_t)(p & 1) * 1024 + (tid << 1);
        const int h2row_c = (p > 0) ? (use_hist ? (p - 1) : ((p - 1) & 1)) : 0;
        const u64* h2p = h2t + (size_t)h2row_c * 1024 + (tid << 1);
        const u32 want1 = (u32)p;
        const u32 want2 = (p >= 2) ? (u32)p : 0u;

        const int tx = (p < TSTEPS) ? p : 0;
        const float2 xv = *(const float2*)(x + (size_t)tx * DIN + (c << 1));

        u64 v1a, v1b, v2a, v2b;
        {
            int guard = 0;
            for (;;) {
                v1a = ld_pair(h1p);     v1b = ld_pair(h1p + 1);
                v2a = ld_pair(h2p);     v2b = ld_pair(h2p + 1);
                if ((PTAG(v1a) == want1) & (PTAG(v1b) == want1) &
                    (PTAG(v2a) == want2) & (PTAG(v2b) == want2)) break;
                if (++guard > (1 << 15)) break;  // hang insurance only
            }
        }
        float sa0 = PVAL(v1a), sa1 = PVAL(v1b);
        float sb0 = PVAL(v2a), sb1 = PVAL(v2b);

        // keepalive: W1 must be VGPR-resident here every phase
        PIN_W1();

        *(float2*)(h1s + sdst) = make_float2(sa0, sa1);
        *(float2*)(h2s + sdst) = make_float2(sb0, sb1);

        // ---- fallback out-path (no hist workspace): WG0, out(p-2) ----
        if (!use_hist && wg == 0 && p >= 2) {
            const float2 wo0 = *(const float2*)(Wout + (tid << 1));
            const float2 wo1 = *(const float2*)(Wout + HID + (tid << 1));
            float q0 = wo0.x * sb0 + wo0.y * sb1;
            float q1 = wo1.x * sb0 + wo1.y * sb1;
            #pragma unroll
            for (int m = 1; m < 64; m <<= 1) {
                q0 += __shfl_xor(q0, m);
                q1 += __shfl_xor(q1, m);
            }
            if (lane == 0) { red0[wave] = q0; red1[wave] = q1; }
            __syncthreads();
            if (tid == 0) {
                float o0 = bout[0], o1 = bout[1];
                #pragma unroll
                for (int w = 0; w < 8; ++w) { o0 += red0[w]; o1 += red1[w]; }
                out[2*(p-2)+0] = o0;
                out[2*(p-2)+1] = o1;
            }
        }
        __syncthreads();

        // ---- dots: a* = Whh1 . h1prev (+x)        [layer 1, t=p]
        //            e* = Wih2 . h1prev + Whh2 . h2prev [layer 2, t=p-1]
        float a0=0.f, a1=0.f, a2=0.f, a3=0.f;
        float e0=0.f, e1=0.f, e2=0.f, e3=0.f;
        const float* hb = h1s + sbase;
        const float* gb = h2s + sbase;
        GSTEP(0, w1a);
        GSTEP(1, w1b);
        GSTEP(2, w1c);
        GSTEP(3, w1d);
        GSTEP(4, w1e);
        GSTEP(5, w1f);
        GSTEP(6, w1g);
        GSTEP(7, w1h);
        a0 = fmaf(wx.x, xv.x, a0);
        a1 = fmaf(wx.y, xv.y, a1);

        float accA = (a0 + a1) + (a2 + a3);
        float accB = (e0 + e1) + (e2 + e3);
        accA += __shfl_xor(accA, 1);   accB += __shfl_xor(accB, 1);
        accA += __shfl_xor(accA, 2);   accB += __shfl_xor(accB, 2);
        accA += __shfl_xor(accA, 4);   accB += __shfl_xor(accB, 4);
        accA += __shfl_xor(accA, 8);   accB += __shfl_xor(accB, 8);
        accA += __shfl_xor(accA, 16);  accB += __shfl_xor(accB, 16);
        if (c == 0) {
            float vA = accA + bsum1;
            float vB = accB + bsum2;
            g1[gate][rsub] = (gate == 2) ? tanh_f(vA) : sigmoid_f(vA);
            g2[gate][rsub] = (gate == 2) ? tanh_f(vB) : sigmoid_f(vB);
        }
        __syncthreads();

        // ---- state updates + tagged publication (no barrier) ----
        if (p < TSTEPS && tid < 4) {
            float iv = g1[0][tid], fv = g1[1][tid];
            float gv = g1[2][tid], ov = g1[3][tid];
            float cn = fv * c1s[tid] + iv * gv;
            c1s[tid] = cn;
            st_pair(h1t + (size_t)((p + 1) & 1) * 1024 + (wg << 2) + tid,
                    ov * tanh_f(cn), (u32)(p + 1));
        }
        if (p >= 1 && tid >= 4 && tid < 8) {
            int u = tid - 4;
            float iv = g2[0][u], fv = g2[1][u];
            float gv = g2[2][u], ov = g2[3][u];
            float cn = fv * c2s[u] + iv * gv;
            c2s[u] = cn;
            const int wr = use_hist ? p : (p & 1);
            st_pair(h2t + (size_t)wr * 1024 + (wg << 2) + u,
                    ov * tanh_f(cn), (u32)(p + 1));
        }
        // no grid barrier: next phase's poll is the synchronization
    }

    // ---- epilogue ----
    if (use_hist) {
        const float2 wo0 = *(const float2*)(Wout + (tid << 1));
        const float2 wo1 = *(const float2*)(Wout + HID + (tid << 1));
        const float bo0 = bout[0], bo1 = bout[1];
        for (int i = 0; i < 16; ++i) {
            const int t = (wg << 4) + i;
            const u64* hp = h2t + (size_t)(t + 1) * 1024 + (tid << 1);
            const u32 want = (u32)(t + 2);
            u64 va, vb; int guard = 0;
            for (;;) {
                va = ld_pair(hp); vb = ld_pair(hp + 1);
                if ((PTAG(va) == want) && (PTAG(vb) == want)) break;
                if (++guard > (1 << 15)) break;
            }
            float h0 = PVAL(va), h1v = PVAL(vb);
            float q0 = wo0.x * h0 + wo0.y * h1v;
            float q1 = wo1.x * h0 + wo1.y * h1v;
            #pragma unroll
            for (int m = 1; m < 64; m <<= 1) {
                q0 += __shfl_xor(q0, m);
                q1 += __shfl_xor(q1, m);
            }
            if (lane == 0) { red0[wave] = q0; red1[wave] = q1; }
            __syncthreads();
            if (tid == 0) {
                float o0 = bo0, o1 = bo1;
                #pragma unroll
                for (int w = 0; w < 8; ++w) { o0 += red0[w]; o1 += red1[w]; }
                out[2*t+0] = o0;
                out[2*t+1] = o1;
            }
            __syncthreads();
        }
    } else if (wg == 0) {
        // final out[T-1]: h2(T-1) written phase TSTEPS -> row TSTEPS&1 = 0,
        // tag TSTEPS+1
        const float2 wo0 = *(const float2*)(Wout + (tid << 1));
        const float2 wo1 = *(const float2*)(Wout + HID + (tid << 1));
        const u64* hp = h2t + (size_t)(TSTEPS & 1) * 1024 + (tid << 1);
        const u32 want = (u32)(TSTEPS + 1);
        u64 va, vb; int guard = 0;
        for (;;) {
            va = ld_pair(hp); vb = ld_pair(hp + 1);
            if ((PTAG(va) == want) && (PTAG(vb) == want)) break;
            if (++guard > (1 << 15)) break;
        }
        float h0 = PVAL(va), h1v = PVAL(vb);
        float q0 = wo0.x * h0 + wo0.y * h1v;
        float q1 = wo1.x * h0 + wo1.y * h1v;
        #pragma unroll
        for (int m = 1; m < 64; m <<= 1) {
            q0 += __shfl_xor(q0, m);
            q1 += __shfl_xor(q1, m);
        }
        if (lane == 0) { red0[wave] = q0; red1[wave] = q1; }
        __syncthreads();
        if (tid == 0) {
            float o0 = bout[0], o1 = bout[1];
            #pragma unroll
            for (int w = 0; w < 8; ++w) { o0 += red0[w]; o1 += red1[w]; }
            out[2*(TSTEPS-1)+0] = o0;
            out[2*(TSTEPS-1)+1] = o1;
        }
    }
}

extern "C" void kernel_launch(void* const* d_in, const int* in_sizes, int n_in,
                              void* d_out, int out_size, void* d_ws, size_t ws_size,
                              hipStream_t stream)
{
    const float* x    = (const float*)d_in[0];
    const float* Wih1 = (const float*)d_in[1];
    const float* Whh1 = (const float*)d_in[2];
    const float* bih1 = (const float*)d_in[3];
    const float* bhh1 = (const float*)d_in[4];
    const float* Wih2 = (const float*)d_in[5];
    const float* Whh2 = (const float*)d_in[6];
    const float* bih2 = (const float*)d_in[7];
    const float* bhh2 = (const float*)d_in[8];
    const float* Wout = (const float*)d_in[9];
    const float* bout = (const float*)d_in[10];
    float* out = (float*)d_out;
    u64*   ws  = (u64*)d_ws;

    const int use_hist = (ws_size >= WS_NEED_BYTES) ? 1 : 0;

    // allow >64KB dynamic LDS (idempotent, not stream-ordered: capture-safe)
    (void)hipFuncSetAttribute((const void*)lstm_persistent,
                              hipFuncAttributeMaxDynamicSharedMemorySize,
                              DYN_LDS_BYTES);

    // zero h1 slots + h2 rows 0..1 (ws re-poisoned 0xAA before every call;
    // poison can never equal a wanted tag, so un-zeroed hist rows are safe)
    hipMemsetAsync(d_ws, 0, WS_ZERO_BYTES, stream);

    hipLaunchKernelGGL(lstm_persistent, dim3(NWG), dim3(TPB), DYN_LDS_BYTES,
                       stream,
                       x, Wih1, Whh1, bih1, bhh1,
                       Wih2, Whh2, bih2, bhh2,
                       Wout, bout, out, ws, use_hist);
}

// Round 8
// 8250.646 us; speedup vs baseline: 2.1521x; 2.1521x over previous
//
#include <hip/hip_runtime.h>
#include <math.h>

// LSTM_53171695124900: 2-layer LSTM, H=1024, I=64, O=2, T=4096.
// Persistent kernel, 256 WGs x 512 threads.
// Round-8 change vs round-7 (17.8ms): r7 proved weight storage is NOT the
// bottleneck (LDS weights == spilled scratch, FETCH unchanged) -> the floor
// is the per-phase serial chain with ~2 exposed IC round trips. Restructure:
//   A-part: poll h1 (blocking) + issue h2 loads early; stage h1; dot
//           accA=W_hh1.h1 (+x) AND partial accB=W_ih2.h1 (h1 read once);
//           reduce; g1 gates; verify/stage h2; sync; PUBLISH h1(p) NOW.
//   B-part: accB += W_hh2.h2; reduce; g2 gates; sync; publish h2/hist.
// In steady state h1(p) is published ~one B-part (~1us) before consumers
// poll it -> next-phase polls hit on first try; IC latency hidden under B.
// Sync/data protocol (tagged 8B pairs, relaxed agent atomics) unchanged
// from r6/r7 (proven, absmax 6.1e-5). Weights: W_hh1 regs, W_ih2/W_hh2 LDS.

#define HID 1024
#define DIN 64
#define TSTEPS 4096
#define NWG 256
#define TPB 512

typedef unsigned long long u64;
typedef unsigned int u32;

// ws layout in u64 (8B tagged pairs):
//   [0, 2048)                 : h1 pairs, 2 slots x 1024
//   [2048, 2048 + 4097*1024)  : h2 pairs; hist mode = row per phase,
//                               fallback mode = rows (phase & 1)
#define H2_OFF 2048
#define WS_NEED_U64 (2048ull + 4097ull * 1024ull)
#define WS_NEED_BYTES (WS_NEED_U64 * 8ull)
#define WS_ZERO_BYTES 32768   // h1 slots (16KB) + h2 rows 0..1 (16KB)

// dynamic LDS: 16*512 float4 weights (128KB) + h1s/h2s staging (9216B)
#define WLDS_F4 (16 * 512)
#define DYN_LDS_BYTES (WLDS_F4 * 16 + 2 * 1152 * 4)

__device__ __forceinline__ float sigmoid_f(float v) {
    return 1.0f / (1.0f + __expf(-v));
}
__device__ __forceinline__ float tanh_f(float v) {
    return 2.0f / (1.0f + __expf(-2.0f * v)) - 1.0f;
}

// relaxed agent-scope 8B atomics: coherent at IC, no cache-maintenance insts
__device__ __forceinline__ void st_pair(u64* p, float h, u32 tag) {
    u64 pk = ((u64)tag << 32) | (u64)__float_as_uint(h);
    __hip_atomic_store(p, pk, __ATOMIC_RELAXED, __HIP_MEMORY_SCOPE_AGENT);
}
__device__ __forceinline__ u64 ld_pair(const u64* p) {
    return __hip_atomic_load(p, __ATOMIC_RELAXED, __HIP_MEMORY_SCOPE_AGENT);
}
#define PTAG(v) ((u32)((v) >> 32))
#define PVAL(v) (__uint_as_float((u32)(v)))

#define PIN4(v) asm volatile("" : "+v"((v).x), "+v"((v).y), "+v"((v).z), "+v"((v).w))
#define PIN_W1() do { \
    PIN4(w1a); PIN4(w1b); PIN4(w1c); PIN4(w1d); \
    PIN4(w1e); PIN4(w1f); PIN4(w1g); PIN4(w1h); \
} while (0)

// A-part k-chunk j: W1 (regs) . hv -> accA;  W2 (LDS) . hv -> accB partial
#define ASTEP(j, W1) do {                                           \
    float4 hv = *(const float4*)(hb + 4*(j));                       \
    float4 w2 = wlds[(j)*512 + tid];                                \
    a0 = fmaf((W1).x, hv.x, a0); a1 = fmaf((W1).y, hv.y, a1);       \
    a2 = fmaf((W1).z, hv.z, a2); a3 = fmaf((W1).w, hv.w, a3);       \
    e0 = fmaf(w2.x, hv.x, e0); e1 = fmaf(w2.y, hv.y, e1);           \
    e2 = fmaf(w2.z, hv.z, e2); e3 = fmaf(w2.w, hv.w, e3);           \
} while (0)

// B-part k-chunk j: W3 (LDS) . gv -> accB
#define BSTEP(j) do {                                               \
    float4 gv = *(const float4*)(gb + 4*(j));                       \
    float4 w3 = wlds[(8+(j))*512 + tid];                            \
    e0 = fmaf(w3.x, gv.x, e0); e1 = fmaf(w3.y, gv.y, e1);           \
    e2 = fmaf(w3.z, gv.z, e2); e3 = fmaf(w3.w, gv.w, e3);           \
} while (0)

__global__ void
__attribute__((amdgpu_flat_work_group_size(TPB, TPB), amdgpu_waves_per_eu(2, 2)))
lstm_persistent(
    const float* __restrict__ x,
    const float* __restrict__ Wih1, const float* __restrict__ Whh1,
    const float* __restrict__ bih1, const float* __restrict__ bhh1,
    const float* __restrict__ Wih2, const float* __restrict__ Whh2,
    const float* __restrict__ bih2, const float* __restrict__ bhh2,
    const float* __restrict__ Wout, const float* __restrict__ bout,
    float* __restrict__ out, u64* __restrict__ ws, int use_hist)
{
    const int wg   = blockIdx.x;          // 0..255
    const int tid  = threadIdx.x;         // 0..511
    const int wave = tid >> 6;            // 0..7
    const int lane = tid & 63;
    const int gate = tid >> 7;            // 0..3 (i,f,g,o)
    const int rsub = (tid >> 5) & 3;      // local unit 0..3
    const int c    = tid & 31;            // k-chunk 0..31
    const int row  = gate * HID + (wg << 2) + rsub;   // gate row in [0,4096)
    const int kbase = c << 5;

    u64* h1t = ws;
    u64* h2t = ws + H2_OFF;

    // ---- dynamic LDS carve ----
    extern __shared__ __align__(16) char smem[];
    float4* wlds = (float4*)smem;                         // 128KB weights
    float*  h1s  = (float*)(smem + WLDS_F4 * 16);         // 1152 f32
    float*  h2s  = h1s + 1152;                            // 1152 f32

    // ---- one-time: stage W_ih2/W_hh2 rows into LDS (conflict-free) ----
    {
        const float4* q2 = (const float4*)(Wih2 + (size_t)row * HID + kbase);
        const float4* q3 = (const float4*)(Whh2 + (size_t)row * HID + kbase);
        #pragma unroll
        for (int j = 0; j < 8; ++j) wlds[j * 512 + tid] = q2[j];
        #pragma unroll
        for (int j = 0; j < 8; ++j) wlds[(8 + j) * 512 + tid] = q3[j];
    }

    // ---- W_hh1 row chunk in registers: 8 named float4 SSA values ----
    const float4* p1 = (const float4*)(Whh1 + (size_t)row * HID + kbase);
    float4 w1a = p1[0], w1b = p1[1], w1c = p1[2], w1d = p1[3];
    float4 w1e = p1[4], w1f = p1[5], w1g = p1[6], w1h = p1[7];
    PIN_W1();

    const float2 wx = *(const float2*)(Wih1 + (size_t)row * DIN + (c << 1));
    const float bsum1 = bih1[row] + bhh1[row];
    const float bsum2 = bih2[row] + bhh2[row];

    __shared__ float g1[4][4], g2[4][4];
    __shared__ float c1s[4], c2s[4];
    __shared__ float red0[8], red1[8];
    if (tid < 4) { c1s[tid] = 0.0f; c2s[tid] = 0.0f; }

    // element e=2*tid lands at 36*(e>>5) + (e&31); read base 36*c
    const int sdst = 36 * (tid >> 4) + ((tid << 1) & 31);
    const int sbase = 36 * c;

    __syncthreads();   // wlds staged, c-state zeroed

    for (int p = 0; p <= TSTEPS; ++p) {
        const u64* h1p = h1t + (size_t)(p & 1) * 1024 + (tid << 1);
        const int h2row_c = (p > 0) ? (use_hist ? (p - 1) : ((p - 1) & 1)) : 0;
        const u64* h2p = h2t + (size_t)h2row_c * 1024 + (tid << 1);
        const u32 want1 = (u32)p;
        const u32 want2 = (p >= 2) ? (u32)p : 0u;

        const int tx = (p < TSTEPS) ? p : 0;
        const float2 xv = *(const float2*)(x + (size_t)tx * DIN + (c << 1));

        // ---- blocking poll: h1(p-1), tag p (published mid-phase p-1,
        //      ~one B-part ago -> usually first-try hit) ----
        u64 v1a, v1b;
        {
            int guard = 0;
            for (;;) {
                v1a = ld_pair(h1p); v1b = ld_pair(h1p + 1);
                if ((PTAG(v1a) == want1) & (PTAG(v1b) == want1)) break;
                if (++guard > (1 << 17)) break;  // hang insurance only
            }
        }
        // early h2 read attempt (verified after the A-dot)
        u64 v2a = ld_pair(h2p), v2b = ld_pair(h2p + 1);

        PIN_W1();   // keepalive: W1 VGPR-resident every phase

        *(float2*)(h1s + sdst) = make_float2(PVAL(v1a), PVAL(v1b));
        __syncthreads();   // S1: h1s staged

        // ---- A-dot: accA = W_hh1.h1 (+x); accB partial = W_ih2.h1 ----
        float a0=0.f, a1=0.f, a2=0.f, a3=0.f;
        float e0=0.f, e1=0.f, e2=0.f, e3=0.f;
        const float* hb = h1s + sbase;
        ASTEP(0, w1a); ASTEP(1, w1b); ASTEP(2, w1c); ASTEP(3, w1d);
        ASTEP(4, w1e); ASTEP(5, w1f); ASTEP(6, w1g); ASTEP(7, w1h);
        a0 = fmaf(wx.x, xv.x, a0);
        a1 = fmaf(wx.y, xv.y, a1);

        float accA = (a0 + a1) + (a2 + a3);
        accA += __shfl_xor(accA, 1);
        accA += __shfl_xor(accA, 2);
        accA += __shfl_xor(accA, 4);
        accA += __shfl_xor(accA, 8);
        accA += __shfl_xor(accA, 16);
        if (c == 0) {
            float vA = accA + bsum1;
            g1[gate][rsub] = (gate == 2) ? tanh_f(vA) : sigmoid_f(vA);
        }

        // ---- finish h2 poll (usually already satisfied) + stage ----
        {
            int guard = 0;
            while (!((PTAG(v2a) == want2) & (PTAG(v2b) == want2))) {
                v2a = ld_pair(h2p); v2b = ld_pair(h2p + 1);
                if (++guard > (1 << 17)) break;  // hang insurance only
            }
        }
        float sb0 = PVAL(v2a), sb1 = PVAL(v2b);
        *(float2*)(h2s + sdst) = make_float2(sb0, sb1);
        __syncthreads();   // S2: g1 + h2s ready

        // ---- EARLY h1 publication: before the heavy B-part ----
        if (p < TSTEPS && tid < 4) {
            float iv = g1[0][tid], fv = g1[1][tid];
            float gv = g1[2][tid], ov = g1[3][tid];
            float cn = fv * c1s[tid] + iv * gv;
            c1s[tid] = cn;
            st_pair(h1t + (size_t)((p + 1) & 1) * 1024 + (wg << 2) + tid,
                    ov * tanh_f(cn), (u32)(p + 1));
        }

        // ---- B-dot: accB += W_hh2.h2 ----
        const float* gb = h2s + sbase;
        BSTEP(0); BSTEP(1); BSTEP(2); BSTEP(3);
        BSTEP(4); BSTEP(5); BSTEP(6); BSTEP(7);

        float accB = (e0 + e1) + (e2 + e3);
        accB += __shfl_xor(accB, 1);
        accB += __shfl_xor(accB, 2);
        accB += __shfl_xor(accB, 4);
        accB += __shfl_xor(accB, 8);
        accB += __shfl_xor(accB, 16);
        if (c == 0) {
            float vB = accB + bsum2;
            g2[gate][rsub] = (gate == 2) ? tanh_f(vB) : sigmoid_f(vB);
        }
        __syncthreads();   // S3: g2 ready; also fences LDS reuse next phase

        if (p >= 1 && tid >= 4 && tid < 8) {
            int u = tid - 4;
            float iv = g2[0][u], fv = g2[1][u];
            float gv = g2[2][u], ov = g2[3][u];
            float cn = fv * c2s[u] + iv * gv;
            c2s[u] = cn;
            const int wr = use_hist ? p : (p & 1);
            st_pair(h2t + (size_t)wr * 1024 + (wg << 2) + u,
                    ov * tanh_f(cn), (u32)(p + 1));
        }

        // ---- fallback out-path (no hist workspace): WG0, out(p-2) ----
        if (!use_hist && wg == 0 && p >= 2) {
            const float2 wo0 = *(const float2*)(Wout + (tid << 1));
            const float2 wo1 = *(const float2*)(Wout + HID + (tid << 1));
            float q0 = wo0.x * sb0 + wo0.y * sb1;
            float q1 = wo1.x * sb0 + wo1.y * sb1;
            #pragma unroll
            for (int m = 1; m < 64; m <<= 1) {
                q0 += __shfl_xor(q0, m);
                q1 += __shfl_xor(q1, m);
            }
            if (lane == 0) { red0[wave] = q0; red1[wave] = q1; }
            __syncthreads();
            if (tid == 0) {
                float o0 = bout[0], o1 = bout[1];
                #pragma unroll
                for (int w = 0; w < 8; ++w) { o0 += red0[w]; o1 += red1[w]; }
                out[2*(p-2)+0] = o0;
                out[2*(p-2)+1] = o1;
            }
            __syncthreads();
        }
        // no grid barrier: next phase's poll is the synchronization
    }

    // ---- epilogue ----
    if (use_hist) {
        const float2 wo0 = *(const float2*)(Wout + (tid << 1));
        const float2 wo1 = *(const float2*)(Wout + HID + (tid << 1));
        const float bo0 = bout[0], bo1 = bout[1];
        for (int i = 0; i < 16; ++i) {
            const int t = (wg << 4) + i;
            const u64* hp = h2t + (size_t)(t + 1) * 1024 + (tid << 1);
            const u32 want = (u32)(t + 2);
            u64 va, vb; int guard = 0;
            for (;;) {
                va = ld_pair(hp); vb = ld_pair(hp + 1);
                if ((PTAG(va) == want) && (PTAG(vb) == want)) break;
                if (++guard > (1 << 15)) break;
            }
            float h0 = PVAL(va), h1v = PVAL(vb);
            float q0 = wo0.x * h0 + wo0.y * h1v;
            float q1 = wo1.x * h0 + wo1.y * h1v;
            #pragma unroll
            for (int m = 1; m < 64; m <<= 1) {
                q0 += __shfl_xor(q0, m);
                q1 += __shfl_xor(q1, m);
            }
            if (lane == 0) { red0[wave] = q0; red1[wave] = q1; }
            __syncthreads();
            if (tid == 0) {
                float o0 = bo0, o1 = bo1;
                #pragma unroll
                for (int w = 0; w < 8; ++w) { o0 += red0[w]; o1 += red1[w]; }
                out[2*t+0] = o0;
                out[2*t+1] = o1;
            }
            __syncthreads();
        }
    } else if (wg == 0) {
        // final out[T-1]: h2(T-1) written phase TSTEPS -> row TSTEPS&1 = 0,
        // tag TSTEPS+1
        const float2 wo0 = *(const float2*)(Wout + (tid << 1));
        const float2 wo1 = *(const float2*)(Wout + HID + (tid << 1));
        const u64* hp = h2t + (size_t)(TSTEPS & 1) * 1024 + (tid << 1);
        const u32 want = (u32)(TSTEPS + 1);
        u64 va, vb; int guard = 0;
        for (;;) {
            va = ld_pair(hp); vb = ld_pair(hp + 1);
            if ((PTAG(va) == want) && (PTAG(vb) == want)) break;
            if (++guard > (1 << 15)) break;
        }
        float h0 = PVAL(va), h1v = PVAL(vb);
        float q0 = wo0.x * h0 + wo0.y * h1v;
        float q1 = wo1.x * h0 + wo1.y * h1v;
        #pragma unroll
        for (int m = 1; m < 64; m <<= 1) {
            q0 += __shfl_xor(q0, m);
            q1 += __shfl_xor(q1, m);
        }
        if (lane == 0) { red0[wave] = q0; red1[wave] = q1; }
        __syncthreads();
        if (tid == 0) {
            float o0 = bout[0], o1 = bout[1];
            #pragma unroll
            for (int w = 0; w < 8; ++w) { o0 += red0[w]; o1 += red1[w]; }
            out[2*(TSTEPS-1)+0] = o0;
            out[2*(TSTEPS-1)+1] = o1;
        }
    }
}

extern "C" void kernel_launch(void* const* d_in, const int* in_sizes, int n_in,
                              void* d_out, int out_size, void* d_ws, size_t ws_size,
                              hipStream_t stream)
{
    const float* x    = (const float*)d_in[0];
    const float* Wih1 = (const float*)d_in[1];
    const float* Whh1 = (const float*)d_in[2];
    const float* bih1 = (const float*)d_in[3];
    const float* bhh1 = (const float*)d_in[4];
    const float* Wih2 = (const float*)d_in[5];
    const float* Whh2 = (const float*)d_in[6];
    const float* bih2 = (const float*)d_in[7];
    const float* bhh2 = (const float*)d_in[8];
    const float* Wout = (const float*)d_in[9];
    const float* bout = (const float*)d_in[10];
    float* out = (float*)d_out;
    u64*   ws  = (u64*)d_ws;

    const int use_hist = (ws_size >= WS_NEED_BYTES) ? 1 : 0;

    // allow >64KB dynamic LDS (idempotent, not stream-ordered: capture-safe)
    (void)hipFuncSetAttribute((const void*)lstm_persistent,
                              hipFuncAttributeMaxDynamicSharedMemorySize,
                              DYN_LDS_BYTES);

    // zero h1 slots + h2 rows 0..1 (ws re-poisoned 0xAA before every call;
    // poison can never equal a wanted tag, so un-zeroed hist rows are safe)
    hipMemsetAsync(d_ws, 0, WS_ZERO_BYTES, stream);

    hipLaunchKernelGGL(lstm_persistent, dim3(NWG), dim3(TPB), DYN_LDS_BYTES,
                       stream,
                       x, Wih1, Whh1, bih1, bhh1,
                       Wih2, Whh2, bih2, bhh2,
                       Wout, bout, out, ws, use_hist);
}

// Round 10
// 7475.430 us; speedup vs baseline: 2.3753x; 1.1037x over previous
//
#include <hip/hip_runtime.h>
#include <math.h>

// LSTM_53171695124900: 2-layer LSTM, H=1024, I=64, O=2, T=4096.
// Persistent kernel, 256 WGs x 512 threads.
// Round-10 = round-9 with the compile fix ONLY: __builtin_amdgcn_cvt_pkrtz
// returns __fp16x2, __builtin_amdgcn_fdot2 takes _Float16x2 -> union holds
// both vector flavors over the same 4 bytes.
// r9 plan vs r8 (8.25ms, ~2.0us/phase, LDS-pipe bound at 256KB/CU/phase):
// all dot INPUTS f16 (packed half2), f32 accumulate via v_dot2_f32_f16:
//   - W_hh1: 16 packed-half2 VGPRs (was 32 f32)
//   - W_ih2/W_hh2: 64KB LDS (was 128KB), uint4 = 8 f16 per ds_read_b128
//   - h staged to LDS as half2, stride-20-u32 rows
//   - published h / c-state / gates / sync protocol stay f32 (r8 proven:
//     tagged 8B pairs, early h1 publish, A/B split)
// LDS reads: 32 -> 16 b128/thread/phase; dot insts: 96 fma -> 48 dot2.

#define HID 1024
#define DIN 64
#define TSTEPS 4096
#define NWG 256
#define TPB 512

typedef unsigned long long u64;
typedef unsigned int u32;
typedef _Float16 f16x2 __attribute__((ext_vector_type(2)));
typedef __fp16   g16x2 __attribute__((ext_vector_type(2)));

// ws layout in u64 (8B tagged pairs):
//   [0, 2048)                 : h1 pairs, 2 slots x 1024
//   [2048, 2048 + 4097*1024)  : h2 pairs; hist mode = row per phase,
//                               fallback mode = rows (phase & 1)
#define H2_OFF 2048
#define WS_NEED_U64 (2048ull + 4097ull * 1024ull)
#define WS_NEED_BYTES (WS_NEED_U64 * 8ull)
#define WS_ZERO_BYTES 32768   // h1 slots (16KB) + h2 rows 0..1 (16KB)

// dynamic LDS: 8*512 uint4 f16 weights (64KB) + 2 x 640-u32 h staging
#define WLDS_U4 (8 * 512)
#define H1S_OFF (WLDS_U4 * 16)            // bytes
#define H2S_OFF (H1S_OFF + 640 * 4)
#define DYN_LDS_BYTES (H2S_OFF + 640 * 4) // 70656 B

__device__ __forceinline__ float sigmoid_f(float v) {
    return 1.0f / (1.0f + __expf(-v));
}
__device__ __forceinline__ float tanh_f(float v) {
    return 2.0f / (1.0f + __expf(-2.0f * v)) - 1.0f;
}

// relaxed agent-scope 8B atomics: coherent at IC, no cache-maintenance insts
__device__ __forceinline__ void st_pair(u64* p, float h, u32 tag) {
    u64 pk = ((u64)tag << 32) | (u64)__float_as_uint(h);
    __hip_atomic_store(p, pk, __ATOMIC_RELAXED, __HIP_MEMORY_SCOPE_AGENT);
}
__device__ __forceinline__ u64 ld_pair(const u64* p) {
    return __hip_atomic_load(p, __ATOMIC_RELAXED, __HIP_MEMORY_SCOPE_AGENT);
}
#define PTAG(v) ((u32)((v) >> 32))
#define PVAL(v) (__uint_as_float((u32)(v)))

// same 4 bytes seen as u32 / __fp16x2 (cvt_pkrtz) / _Float16x2 (fdot2)
union U32H2 { u32 u; f16x2 h; g16x2 g; };

// pack two f32 -> half2 u32 (v_cvt_pkrtz_f16_f32, single inst)
__device__ __forceinline__ u32 pk2(float a, float b) {
    U32H2 t; t.g = __builtin_amdgcn_cvt_pkrtz(a, b); return t.u;
}

#if defined(__has_builtin)
#if __has_builtin(__builtin_amdgcn_fdot2)
#define HAS_FDOT2 1
#endif
#endif

// f32 += half2 . half2  (v_dot2_f32_f16 when available)
__device__ __forceinline__ float dot2f(u32 a, u32 b, float c) {
    U32H2 x, y; x.u = a; y.u = b;
#ifdef HAS_FDOT2
    return __builtin_amdgcn_fdot2(x.h, y.h, c, false);
#else
    float r = fmaf((float)x.h.x, (float)y.h.x, c);
    return fmaf((float)x.h.y, (float)y.h.y, r);
#endif
}

#define PIN_W1() asm volatile("" : "+v"(w1p0), "+v"(w1p1), "+v"(w1p2), \
    "+v"(w1p3), "+v"(w1p4), "+v"(w1p5), "+v"(w1p6), "+v"(w1p7), \
    "+v"(w1p8), "+v"(w1p9), "+v"(w1pA), "+v"(w1pB), \
    "+v"(w1pC), "+v"(w1pD), "+v"(w1pE), "+v"(w1pF))

// A-step j (j=0..3): 8 h1 elems; W1 (reg half2s) -> accA, W2 (LDS) -> accB
#define ASTEP(j, P0, P1, P2, P3) do {                               \
    uint4 hv = *(const uint4*)(h1s + hbase + 4*(j));                \
    uint4 w2 = wlds[(j)*512 + tid];                                 \
    a0 = dot2f(hv.x, P0, a0); a1 = dot2f(hv.y, P1, a1);             \
    a0 = dot2f(hv.z, P2, a0); a1 = dot2f(hv.w, P3, a1);             \
    e0 = dot2f(hv.x, w2.x, e0); e1 = dot2f(hv.y, w2.y, e1);         \
    e0 = dot2f(hv.z, w2.z, e0); e1 = dot2f(hv.w, w2.w, e1);         \
} while (0)

// B-step j (j=0..3): 8 h2 elems; W3 (LDS) -> accB
#define BSTEP(j) do {                                               \
    uint4 gv = *(const uint4*)(h2s + hbase + 4*(j));                \
    uint4 w3 = wlds[(4+(j))*512 + tid];                             \
    e0 = dot2f(gv.x, w3.x, e0); e1 = dot2f(gv.y, w3.y, e1);         \
    e0 = dot2f(gv.z, w3.z, e0); e1 = dot2f(gv.w, w3.w, e1);         \
} while (0)

__global__ void
__attribute__((amdgpu_flat_work_group_size(TPB, TPB), amdgpu_waves_per_eu(2, 2)))
lstm_persistent(
    const float* __restrict__ x,
    const float* __restrict__ Wih1, const float* __restrict__ Whh1,
    const float* __restrict__ bih1, const float* __restrict__ bhh1,
    const float* __restrict__ Wih2, const float* __restrict__ Whh2,
    const float* __restrict__ bih2, const float* __restrict__ bhh2,
    const float* __restrict__ Wout, const float* __restrict__ bout,
    float* __restrict__ out, u64* __restrict__ ws, int use_hist)
{
    const int wg   = blockIdx.x;          // 0..255
    const int tid  = threadIdx.x;         // 0..511
    const int wave = tid >> 6;            // 0..7
    const int lane = tid & 63;
    const int gate = tid >> 7;            // 0..3 (i,f,g,o)
    const int rsub = (tid >> 5) & 3;      // local unit 0..3
    const int c    = tid & 31;            // k-chunk 0..31
    const int row  = gate * HID + (wg << 2) + rsub;   // gate row in [0,4096)
    const int kbase = c << 5;

    u64* h1t = ws;
    u64* h2t = ws + H2_OFF;

    // ---- dynamic LDS carve ----
    extern __shared__ __align__(16) char smem[];
    uint4* wlds = (uint4*)smem;                  // 64KB f16 weights
    u32*   h1s  = (u32*)(smem + H1S_OFF);        // 640 u32 (stride-20 rows)
    u32*   h2s  = (u32*)(smem + H2S_OFF);        // 640 u32

    // ---- one-time: stage W_ih2/W_hh2 rows into LDS as packed f16 ----
    {
        const float4* q2 = (const float4*)(Wih2 + (size_t)row * HID + kbase);
        const float4* q3 = (const float4*)(Whh2 + (size_t)row * HID + kbase);
        #pragma unroll
        for (int j = 0; j < 4; ++j) {
            float4 qa = q2[2*j], qb = q2[2*j+1];
            wlds[j * 512 + tid] = make_uint4(pk2(qa.x, qa.y), pk2(qa.z, qa.w),
                                             pk2(qb.x, qb.y), pk2(qb.z, qb.w));
        }
        #pragma unroll
        for (int j = 0; j < 4; ++j) {
            float4 qa = q3[2*j], qb = q3[2*j+1];
            wlds[(4+j) * 512 + tid] = make_uint4(pk2(qa.x, qa.y), pk2(qa.z, qa.w),
                                                 pk2(qb.x, qb.y), pk2(qb.z, qb.w));
        }
    }

    // ---- W_hh1 row chunk: 16 packed-half2 u32 registers ----
    const float4* p1 = (const float4*)(Whh1 + (size_t)row * HID + kbase);
    float4 f0 = p1[0], f1 = p1[1], f2 = p1[2], f3 = p1[3];
    float4 f4 = p1[4], f5 = p1[5], f6 = p1[6], f7 = p1[7];
    u32 w1p0 = pk2(f0.x, f0.y), w1p1 = pk2(f0.z, f0.w);
    u32 w1p2 = pk2(f1.x, f1.y), w1p3 = pk2(f1.z, f1.w);
    u32 w1p4 = pk2(f2.x, f2.y), w1p5 = pk2(f2.z, f2.w);
    u32 w1p6 = pk2(f3.x, f3.y), w1p7 = pk2(f3.z, f3.w);
    u32 w1p8 = pk2(f4.x, f4.y), w1p9 = pk2(f4.z, f4.w);
    u32 w1pA = pk2(f5.x, f5.y), w1pB = pk2(f5.z, f5.w);
    u32 w1pC = pk2(f6.x, f6.y), w1pD = pk2(f6.z, f6.w);
    u32 w1pE = pk2(f7.x, f7.y), w1pF = pk2(f7.z, f7.w);
    PIN_W1();

    const float2 wx = *(const float2*)(Wih1 + (size_t)row * DIN + (c << 1));
    const float bsum1 = bih1[row] + bhh1[row];
    const float bsum2 = bih2[row] + bhh2[row];

    __shared__ float g1[4][4], g2[4][4];
    __shared__ float c1s[4], c2s[4];
    __shared__ float red0[8], red1[8];
    if (tid < 4) { c1s[tid] = 0.0f; c2s[tid] = 0.0f; }

    // h staging: chunk rows of 16 half2-u32 + 4 pad (stride 20 u32, 80B)
    const int sdst = 20 * (tid >> 4) + (tid & 15);
    const int hbase = 20 * c;

    __syncthreads();   // wlds staged, c-state zeroed

    for (int p = 0; p <= TSTEPS; ++p) {
        const u64* h1p = h1t + (size_t)(p & 1) * 1024 + (tid << 1);
        const int h2row_c = (p > 0) ? (use_hist ? (p - 1) : ((p - 1) & 1)) : 0;
        const u64* h2p = h2t + (size_t)h2row_c * 1024 + (tid << 1);
        const u32 want1 = (u32)p;
        const u32 want2 = (p >= 2) ? (u32)p : 0u;

        const int tx = (p < TSTEPS) ? p : 0;
        const float2 xv = *(const float2*)(x + (size_t)tx * DIN + (c << 1));

        // ---- blocking poll: h1(p-1), tag p (published mid-phase p-1) ----
        u64 v1a, v1b;
        {
            int guard = 0;
            for (;;) {
                v1a = ld_pair(h1p); v1b = ld_pair(h1p + 1);
                if ((PTAG(v1a) == want1) & (PTAG(v1b) == want1)) break;
                if (++guard > (1 << 17)) break;  // hang insurance only
            }
        }
        // early h2 read attempt (verified after the A-dot)
        u64 v2a = ld_pair(h2p), v2b = ld_pair(h2p + 1);

        PIN_W1();   // keepalive: W1 VGPR-resident every phase

        h1s[sdst] = pk2(PVAL(v1a), PVAL(v1b));
        __syncthreads();   // S1: h1s staged

        // ---- A-dot: accA = W_hh1.h1 (+x); accB partial = W_ih2.h1 ----
        float a0 = 0.f, a1 = 0.f, e0 = 0.f, e1 = 0.f;
        ASTEP(0, w1p0, w1p1, w1p2, w1p3);
        ASTEP(1, w1p4, w1p5, w1p6, w1p7);
        ASTEP(2, w1p8, w1p9, w1pA, w1pB);
        ASTEP(3, w1pC, w1pD, w1pE, w1pF);
        a0 = fmaf(wx.x, xv.x, a0);
        a1 = fmaf(wx.y, xv.y, a1);

        float accA = a0 + a1;
        accA += __shfl_xor(accA, 1);
        accA += __shfl_xor(accA, 2);
        accA += __shfl_xor(accA, 4);
        accA += __shfl_xor(accA, 8);
        accA += __shfl_xor(accA, 16);
        if (c == 0) {
            float vA = accA + bsum1;
            g1[gate][rsub] = (gate == 2) ? tanh_f(vA) : sigmoid_f(vA);
        }

        // ---- finish h2 poll (usually already satisfied) + stage ----
        {
            int guard = 0;
            while (!((PTAG(v2a) == want2) & (PTAG(v2b) == want2))) {
                v2a = ld_pair(h2p); v2b = ld_pair(h2p + 1);
                if (++guard > (1 << 17)) break;  // hang insurance only
            }
        }
        float sb0 = PVAL(v2a), sb1 = PVAL(v2b);
        h2s[sdst] = pk2(sb0, sb1);
        __syncthreads();   // S2: g1 + h2s ready

        // ---- EARLY h1 publication: before the heavy B-part ----
        if (p < TSTEPS && tid < 4) {
            float iv = g1[0][tid], fv = g1[1][tid];
            float gv = g1[2][tid], ov = g1[3][tid];
            float cn = fv * c1s[tid] + iv * gv;
            c1s[tid] = cn;
            st_pair(h1t + (size_t)((p + 1) & 1) * 1024 + (wg << 2) + tid,
                    ov * tanh_f(cn), (u32)(p + 1));
        }

        // ---- B-dot: accB += W_hh2.h2 ----
        BSTEP(0); BSTEP(1); BSTEP(2); BSTEP(3);

        float accB = e0 + e1;
        accB += __shfl_xor(accB, 1);
        accB += __shfl_xor(accB, 2);
        accB += __shfl_xor(accB, 4);
        accB += __shfl_xor(accB, 8);
        accB += __shfl_xor(accB, 16);
        if (c == 0) {
            float vB = accB + bsum2;
            g2[gate][rsub] = (gate == 2) ? tanh_f(vB) : sigmoid_f(vB);
        }
        __syncthreads();   // S3: g2 ready; also fences LDS reuse next phase

        if (p >= 1 && tid >= 4 && tid < 8) {
            int u = tid - 4;
            float iv = g2[0][u], fv = g2[1][u];
            float gv = g2[2][u], ov = g2[3][u];
            float cn = fv * c2s[u] + iv * gv;
            c2s[u] = cn;
            const int wr = use_hist ? p : (p & 1);
            st_pair(h2t + (size_t)wr * 1024 + (wg << 2) + u,
                    ov * tanh_f(cn), (u32)(p + 1));
        }

        // ---- fallback out-path (no hist workspace): WG0, out(p-2) ----
        if (!use_hist && wg == 0 && p >= 2) {
            const float2 wo0 = *(const float2*)(Wout + (tid << 1));
            const float2 wo1 = *(const float2*)(Wout + HID + (tid << 1));
            float q0 = wo0.x * sb0 + wo0.y * sb1;
            float q1 = wo1.x * sb0 + wo1.y * sb1;
            #pragma unroll
            for (int m = 1; m < 64; m <<= 1) {
                q0 += __shfl_xor(q0, m);
                q1 += __shfl_xor(q1, m);
            }
            if (lane == 0) { red0[wave] = q0; red1[wave] = q1; }
            __syncthreads();
            if (tid == 0) {
                float o0 = bout[0], o1 = bout[1];
                #pragma unroll
                for (int w = 0; w < 8; ++w) { o0 += red0[w]; o1 += red1[w]; }
                out[2*(p-2)+0] = o0;
                out[2*(p-2)+1] = o1;
            }
            __syncthreads();
        }
        // no grid barrier: next phase's poll is the synchronization
    }

    // ---- epilogue ----
    if (use_hist) {
        const float2 wo0 = *(const float2*)(Wout + (tid << 1));
        const float2 wo1 = *(const float2*)(Wout + HID + (tid << 1));
        const float bo0 = bout[0], bo1 = bout[1];
        for (int i = 0; i < 16; ++i) {
            const int t = (wg << 4) + i;
            const u64* hp = h2t + (size_t)(t + 1) * 1024 + (tid << 1);
            const u32 want = (u32)(t + 2);
            u64 va, vb; int guard = 0;
            for (;;) {
                va = ld_pair(hp); vb = ld_pair(hp + 1);
                if ((PTAG(va) == want) && (PTAG(vb) == want)) break;
                if (++guard > (1 << 15)) break;
            }
            float h0 = PVAL(va), h1v = PVAL(vb);
            float q0 = wo0.x * h0 + wo0.y * h1v;
            float q1 = wo1.x * h0 + wo1.y * h1v;
            #pragma unroll
            for (int m = 1; m < 64; m <<= 1) {
                q0 += __shfl_xor(q0, m);
                q1 += __shfl_xor(q1, m);
            }
            if (lane == 0) { red0[wave] = q0; red1[wave] = q1; }
            __syncthreads();
            if (tid == 0) {
                float o0 = bo0, o1 = bo1;
                #pragma unroll
                for (int w = 0; w < 8; ++w) { o0 += red0[w]; o1 += red1[w]; }
                out[2*t+0] = o0;
                out[2*t+1] = o1;
            }
            __syncthreads();
        }
    } else if (wg == 0) {
        // final out[T-1]: h2(T-1) written phase TSTEPS -> row TSTEPS&1 = 0,
        // tag TSTEPS+1
        const float2 wo0 = *(const float2*)(Wout + (tid << 1));
        const float2 wo1 = *(const float2*)(Wout + HID + (tid << 1));
        const u64* hp = h2t + (size_t)(TSTEPS & 1) * 1024 + (tid << 1);
        const u32 want = (u32)(TSTEPS + 1);
        u64 va, vb; int guard = 0;
        for (;;) {
            va = ld_pair(hp); vb = ld_pair(hp + 1);
            if ((PTAG(va) == want) && (PTAG(vb) == want)) break;
            if (++guard > (1 << 15)) break;
        }
        float h0 = PVAL(va), h1v = PVAL(vb);
        float q0 = wo0.x * h0 + wo0.y * h1v;
        float q1 = wo1.x * h0 + wo1.y * h1v;
        #pragma unroll
        for (int m = 1; m < 64; m <<= 1) {
            q0 += __shfl_xor(q0, m);
            q1 += __shfl_xor(q1, m);
        }
        if (lane == 0) { red0[wave] = q0; red1[wave] = q1; }
        __syncthreads();
        if (tid == 0) {
            float o0 = bout[0], o1 = bout[1];
            #pragma unroll
            for (int w = 0; w < 8; ++w) { o0 += red0[w]; o1 += red1[w]; }
            out[2*(TSTEPS-1)+0] = o0;
            out[2*(TSTEPS-1)+1] = o1;
        }
    }
}

extern "C" void kernel_launch(void* const* d_in, const int* in_sizes, int n_in,
                              void* d_out, int out_size, void* d_ws, size_t ws_size,
                              hipStream_t stream)
{
    const float* x    = (const float*)d_in[0];
    const float* Wih1 = (const float*)d_in[1];
    const float* Whh1 = (const float*)d_in[2];
    const float* bih1 = (const float*)d_in[3];
    const float* bhh1 = (const float*)d_in[4];
    const float* Wih2 = (const float*)d_in[5];
    const float* Whh2 = (const float*)d_in[6];
    const float* bih2 = (const float*)d_in[7];
    const float* bhh2 = (const float*)d_in[8];
    const float* Wout = (const float*)d_in[9];
    const float* bout = (const float*)d_in[10];
    float* out = (float*)d_out;
    u64*   ws  = (u64*)d_ws;

    const int use_hist = (ws_size >= WS_NEED_BYTES) ? 1 : 0;

    // allow >64KB dynamic LDS (idempotent, not stream-ordered: capture-safe)
    (void)hipFuncSetAttribute((const void*)lstm_persistent,
                              hipFuncAttributeMaxDynamicSharedMemorySize,
                              DYN_LDS_BYTES);

    // zero h1 slots + h2 rows 0..1 (ws re-poisoned 0xAA before every call;
    // poison can never equal a wanted tag, so un-zeroed hist rows are safe)
    (void)hipMemsetAsync(d_ws, 0, WS_ZERO_BYTES, stream);

    hipLaunchKernelGGL(lstm_persistent, dim3(NWG), dim3(TPB), DYN_LDS_BYTES,
                       stream,
                       x, Wih1, Whh1, bih1, bhh1,
                       Wih2, Whh2, bih2, bhh2,
                       Wout, bout, out, ws, use_hist);
}